// Round 5
// baseline (1133.975 us; speedup 1.0000x reference)
//
#include <hip/hip_runtime.h>
#include <math.h>

// Problem dims (fixed by reference setup_inputs)
#define BH 8        // heads
#define KK 512      // clusters
#define DD 64       // dim
#define NT 16384    // tokens per head = b*n = 4*4096
#define IDS_N (NT*BH)   // 131072 cluster-id outputs

// ---------------------------------------------------------------------------
// Kernel 1: per-token argmin over 512 clusters + scatter-accumulate sums/counts
// grid = (NT/256, BH), block = 256. Each thread owns one token of one head.
// Distance surrogate: |m_k|^2 - 2 x.m_k  (|x|^2 dropped — constant per token).
// ---------------------------------------------------------------------------
__global__ __launch_bounds__(256) void vq_assign(
    const float* __restrict__ x,       // [NT, BH*DD]
    const float* __restrict__ means,   // [BH, KK, DD]
    float* __restrict__ out_ids,       // [NT*BH] (float-encoded ids)
    float* __restrict__ sums,          // [BH*KK*DD] pre-zeroed (d_out region 2)
    float* __restrict__ counts)        // [BH*KK]    pre-zeroed (d_ws)
{
    const int h = blockIdx.y;
    const int t = blockIdx.x * 256 + threadIdx.x;   // token index within head

    __shared__ float s_m2[KK];

    const float4* __restrict__ mh =
        (const float4*)(means + (size_t)h * KK * DD);

    // Phase A: |m|^2 for this head's 512 clusters -> LDS
    for (int r = threadIdx.x; r < KK; r += 256) {
        const float4* row = mh + r * (DD / 4);
        float a0 = 0.f, a1 = 0.f, a2 = 0.f, a3 = 0.f;
#pragma unroll
        for (int j = 0; j < DD / 4; ++j) {
            float4 m = row[j];
            a0 = fmaf(m.x, m.x, a0);
            a1 = fmaf(m.y, m.y, a1);
            a2 = fmaf(m.z, m.z, a2);
            a3 = fmaf(m.w, m.w, a3);
        }
        s_m2[r] = (a0 + a1) + (a2 + a3);
    }
    __syncthreads();

    // Phase B: token x into registers, pre-scaled by -2 (exact, power of two).
    // dist = |m|^2 + sum((-2x) .* m); original x recovered as -0.5 * xv2.
    float4 xv2[16];
    const float4* __restrict__ xg =
        (const float4*)(x + (size_t)t * (BH * DD) + h * DD);
#pragma unroll
    for (int j = 0; j < 16; ++j) {
        float4 v = xg[j];
        xv2[j] = make_float4(-2.f * v.x, -2.f * v.y, -2.f * v.z, -2.f * v.w);
    }

    // Phase C: argmin over 512 clusters
    float best = 3.4e38f;
    int bid = 0;
    for (int k = 0; k < KK; ++k) {
        const float4* row = mh + k * (DD / 4);   // wave-uniform address -> s_load
        float a0 = s_m2[k], a1 = 0.f, a2 = 0.f, a3 = 0.f;
#pragma unroll
        for (int j = 0; j < 16; ++j) {
            float4 m = row[j];
            a0 = fmaf(xv2[j].x, m.x, a0);
            a1 = fmaf(xv2[j].y, m.y, a1);
            a2 = fmaf(xv2[j].z, m.z, a2);
            a3 = fmaf(xv2[j].w, m.w, a3);
        }
        float dist = (a0 + a1) + (a2 + a3);
        if (dist < best) { best = dist; bid = k; }   // strict < keeps first idx
    }

    // ids output layout: [b, n, h] row-major == t*BH + h
    out_ids[(size_t)t * BH + h] = (float)bid;

    // Phase D: scatter-accumulate (fire-and-forget device-scope atomics).
    // -0.5f * (-2x) == x exactly (pow2 scaling).
    float* srow = sums + ((size_t)h * KK + bid) * DD;
#pragma unroll
    for (int j = 0; j < 16; ++j) {
        atomicAdd(&srow[4 * j + 0], -0.5f * xv2[j].x);
        atomicAdd(&srow[4 * j + 1], -0.5f * xv2[j].y);
        atomicAdd(&srow[4 * j + 2], -0.5f * xv2[j].z);
        atomicAdd(&srow[4 * j + 3], -0.5f * xv2[j].w);
    }
    atomicAdd(&counts[h * KK + bid], 1.0f);
}

// ---------------------------------------------------------------------------
// Kernel 2: finalize EMA update in place over the sums region of d_out.
// updated = 0.001 * sum/(1e-6 + count) + 0.999 * means
// ---------------------------------------------------------------------------
__global__ __launch_bounds__(256) void vq_update(
    const float* __restrict__ means,
    const float* __restrict__ counts,
    float* __restrict__ out_means)   // holds sums on entry, updated on exit
{
    int idx = blockIdx.x * 256 + threadIdx.x;    // [0, BH*KK*DD)
    float cnt = counts[idx >> 6];                // one (h,k) row per 64 lanes -> broadcast
    float s = out_means[idx];
    float nm = s / (1e-6f + cnt);
    out_means[idx] = 0.001f * nm + 0.999f * means[idx];
}

extern "C" void kernel_launch(void* const* d_in, const int* in_sizes, int n_in,
                              void* d_out, int out_size, void* d_ws, size_t ws_size,
                              hipStream_t stream) {
    const float* x     = (const float*)d_in[0];   // [4,4096,512] f32
    const float* means = (const float*)d_in[1];   // [8,512,64]  f32

    float* out      = (float*)d_out;
    float* out_ids  = out;            // first 131072 floats
    float* sums     = out + IDS_N;    // next 262144 floats (becomes updated_means)
    float* counts   = (float*)d_ws;   // 4096 floats of scratch

    // zero the accumulators (d_out/d_ws are poisoned before every call)
    hipMemsetAsync(sums, 0, (size_t)BH * KK * DD * sizeof(float), stream);
    hipMemsetAsync(counts, 0, (size_t)BH * KK * sizeof(float), stream);

    dim3 grid(NT / 256, BH);
    vq_assign<<<grid, dim3(256), 0, stream>>>(x, means, out_ids, sums, counts);

    vq_update<<<(BH * KK * DD) / 256, 256, 0, stream>>>(means, counts, sums);
}

// Round 8
// 691.874 us; speedup vs baseline: 1.6390x; 1.6390x over previous
//
#include <hip/hip_runtime.h>
#include <math.h>

// Problem dims (fixed by reference setup_inputs)
#define BH 8        // heads
#define KK 512      // clusters
#define DD 64       // dim
#define NT 16384    // tokens per head = b*n = 4*4096
#define IDS_N (NT*BH)   // 131072 cluster-id outputs

// ws layout (u32 words):
//   [0,           4096)   g_hist  — counts per (h,k)
//   [4096,        8192)   cursor  — scan offsets, then offset+count after scatter
//   [8192, 8192+131072)   tokbuf  — token indices bucketed per (h,k)

// ---------------------------------------------------------------------------
// Kernel 1: per-token argmin over 512 clusters. Writes float-encoded ids and
// an LDS-aggregated histogram (few global atomics, int, ~200/block).
// grid = (NT/256, BH), block = 256.
// ---------------------------------------------------------------------------
__global__ __launch_bounds__(256) void vq_assign(
    const float* __restrict__ x,       // [NT, BH*DD]
    const float* __restrict__ means,   // [BH, KK, DD]
    float* __restrict__ out_ids,       // [NT*BH]
    unsigned int* __restrict__ g_hist) // [BH*KK] pre-zeroed
{
    const int h = blockIdx.y;
    const int t = blockIdx.x * 256 + threadIdx.x;   // token index within head

    __shared__ float s_m2[KK];
    __shared__ unsigned int s_hist[KK];

    const float4* __restrict__ mh =
        (const float4*)(means + (size_t)h * KK * DD);

    // Phase A: |m|^2 for this head's 512 clusters -> LDS; zero local hist
    for (int r = threadIdx.x; r < KK; r += 256) {
        const float4* row = mh + r * (DD / 4);
        float a0 = 0.f, a1 = 0.f, a2 = 0.f, a3 = 0.f;
#pragma unroll
        for (int j = 0; j < DD / 4; ++j) {
            float4 m = row[j];
            a0 = fmaf(m.x, m.x, a0);
            a1 = fmaf(m.y, m.y, a1);
            a2 = fmaf(m.z, m.z, a2);
            a3 = fmaf(m.w, m.w, a3);
        }
        s_m2[r] = (a0 + a1) + (a2 + a3);
        s_hist[r] = 0u;
    }
    __syncthreads();

    // Phase B: token x into registers, pre-scaled by -2 (exact pow2).
    float4 xv2[16];
    const float4* __restrict__ xg =
        (const float4*)(x + (size_t)t * (BH * DD) + h * DD);
#pragma unroll
    for (int j = 0; j < 16; ++j) {
        float4 v = xg[j];
        xv2[j] = make_float4(-2.f * v.x, -2.f * v.y, -2.f * v.z, -2.f * v.w);
    }

    // Phase C: argmin_k ( |m_k|^2 - 2 x.m_k )
    float best = 3.4e38f;
    int bid = 0;
#pragma unroll 2
    for (int k = 0; k < KK; ++k) {
        const float4* row = mh + k * (DD / 4);   // wave-uniform -> s_load
        float a0 = s_m2[k], a1 = 0.f, a2 = 0.f, a3 = 0.f;
#pragma unroll
        for (int j = 0; j < 16; ++j) {
            float4 m = row[j];
            a0 = fmaf(xv2[j].x, m.x, a0);
            a1 = fmaf(xv2[j].y, m.y, a1);
            a2 = fmaf(xv2[j].z, m.z, a2);
            a3 = fmaf(xv2[j].w, m.w, a3);
        }
        float dist = (a0 + a1) + (a2 + a3);
        if (dist < best) { best = dist; bid = k; }   // strict < = first idx
    }

    out_ids[(size_t)t * BH + h] = (float)bid;   // [b,n,h] layout

    // Phase D: LDS histogram, then sparse flush to global
    atomicAdd(&s_hist[bid], 1u);
    __syncthreads();
    for (int r = threadIdx.x; r < KK; r += 256) {
        unsigned int v = s_hist[r];
        if (v) atomicAdd(&g_hist[h * KK + r], v);
    }
}

// ---------------------------------------------------------------------------
// Kernel 2: per-head exclusive prefix sum of counts -> cursor.
// grid = BH blocks, 512 threads.
// ---------------------------------------------------------------------------
__global__ __launch_bounds__(512) void vq_scan(
    const unsigned int* __restrict__ g_hist,
    unsigned int* __restrict__ cursor)
{
    const int h = blockIdx.x;
    const int tid = threadIdx.x;
    __shared__ unsigned int s[KK];

    unsigned int own = g_hist[h * KK + tid];
    s[tid] = own;
    __syncthreads();
    for (int off = 1; off < KK; off <<= 1) {
        unsigned int v = 0;
        if (tid >= off) v = s[tid - off];
        __syncthreads();
        s[tid] += v;
        __syncthreads();
    }
    cursor[h * KK + tid] = s[tid] - own;   // exclusive
}

// ---------------------------------------------------------------------------
// Kernel 3: scatter token indices into buckets. One cursor atomic per token.
// grid = (NT/256, BH), block = 256.
// ---------------------------------------------------------------------------
__global__ __launch_bounds__(256) void vq_scatter(
    const float* __restrict__ out_ids,
    unsigned int* __restrict__ cursor,
    unsigned int* __restrict__ tokbuf)   // [BH*NT]
{
    const int h = blockIdx.y;
    const int t = blockIdx.x * 256 + threadIdx.x;
    int id = (int)out_ids[(size_t)t * BH + h];
    unsigned int slot = atomicAdd(&cursor[h * KK + id], 1u);
    tokbuf[(size_t)h * NT + slot] = (unsigned int)t;
}

// ---------------------------------------------------------------------------
// Kernel 4: one wave per (h,k): gather-sum bucket rows (lane = dim), fuse EMA.
// grid = BH*KK/4 blocks of 256 (4 waves each). Zero atomics.
// ---------------------------------------------------------------------------
__global__ __launch_bounds__(256) void vq_gather(
    const float* __restrict__ x,
    const float* __restrict__ means,
    const unsigned int* __restrict__ g_hist,
    const unsigned int* __restrict__ cursor,   // now offset+count
    const unsigned int* __restrict__ tokbuf,
    float* __restrict__ out_means)
{
    const int w    = blockIdx.x * 4 + (threadIdx.x >> 6);   // cluster id (h*KK+k)
    const int lane = threadIdx.x & 63;
    const int h    = w >> 9;

    unsigned int cnt = g_hist[w];
    unsigned int off = cursor[w] - cnt;
    const unsigned int* tb = tokbuf + (size_t)h * NT;

    float acc = 0.f;
    for (unsigned int i = 0; i < cnt; ++i) {
        unsigned int tok = tb[off + i];
        acc += x[(size_t)tok * (BH * DD) + h * DD + lane];
    }

    float nm = acc / (1e-6f + (float)cnt);
    float m  = means[(size_t)w * DD + lane];
    out_means[(size_t)w * DD + lane] = 0.001f * nm + 0.999f * m;
}

extern "C" void kernel_launch(void* const* d_in, const int* in_sizes, int n_in,
                              void* d_out, int out_size, void* d_ws, size_t ws_size,
                              hipStream_t stream) {
    const float* x     = (const float*)d_in[0];   // [4,4096,512] f32
    const float* means = (const float*)d_in[1];   // [8,512,64]  f32

    float* out       = (float*)d_out;
    float* out_ids   = out;            // first 131072 floats
    float* out_means = out + IDS_N;    // next 262144 floats

    unsigned int* g_hist = (unsigned int*)d_ws;          // 4096
    unsigned int* cursor = g_hist + BH * KK;             // 4096
    unsigned int* tokbuf = cursor + BH * KK;             // 131072

    // zero hist+cursor (contiguous 32 KB); tokbuf needs no init
    hipMemsetAsync(g_hist, 0, 2 * BH * KK * sizeof(unsigned int), stream);

    dim3 grid(NT / 256, BH);
    vq_assign <<<grid, dim3(256), 0, stream>>>(x, means, out_ids, g_hist);
    vq_scan   <<<BH, dim3(512), 0, stream>>>(g_hist, cursor);
    vq_scatter<<<grid, dim3(256), 0, stream>>>(out_ids, cursor, tokbuf);
    vq_gather <<<(BH * KK) / 4, dim3(256), 0, stream>>>(
        x, means, g_hist, cursor, tokbuf, out_means);
}

// Round 11
// 409.462 us; speedup vs baseline: 2.7694x; 1.6897x over previous
//
#include <hip/hip_runtime.h>
#include <math.h>

// Problem dims (fixed by reference setup_inputs)
#define BH 8        // heads
#define KK 512      // clusters
#define DD 64       // dim
#define NT 16384    // tokens per head = b*n = 4*4096
#define IDS_N (NT*BH)   // 131072 cluster-id outputs
#define CH 128      // clusters staged in LDS per chunk

// ws layout (u32 words):
//   [0,           4096)   g_hist  — counts per (h,k)
//   [4096,        8192)   cursor  — scan offsets, then offset+count after scatter
//   [8192, 8192+131072)   tokbuf  — token indices bucketed per (h,k)

// ---------------------------------------------------------------------------
// Kernel 1: per-token argmin over 512 clusters, codebook staged via LDS in
// 4 chunks of 128 rows (32 KB) -> wave-uniform ds_read broadcast, no global
// latency in the hot loop. grid = (NT/256, BH), block = 256 (2 blocks/CU).
// ---------------------------------------------------------------------------
__global__ __launch_bounds__(256, 4) void vq_assign(
    const float* __restrict__ x,       // [NT, BH*DD]
    const float* __restrict__ means,   // [BH, KK, DD]
    float* __restrict__ out_ids,       // [NT*BH]
    unsigned int* __restrict__ g_hist) // [BH*KK] pre-zeroed
{
    const int h   = blockIdx.y;
    const int tid = threadIdx.x;
    const int t   = blockIdx.x * 256 + tid;   // token index within head

    __shared__ float4 s_mrow[CH * (DD / 4)];  // 32 KB: one chunk of codebook
    __shared__ float  s_m2[KK];               // 2 KB
    __shared__ unsigned int s_hist[KK];       // 2 KB

    const float4* __restrict__ mh =
        (const float4*)(means + (size_t)h * KK * DD);

    // Prologue: |m|^2 for all 512 clusters -> LDS; zero local hist
    for (int r = tid; r < KK; r += 256) {
        const float4* row = mh + r * (DD / 4);
        float a0 = 0.f, a1 = 0.f, a2 = 0.f, a3 = 0.f;
#pragma unroll
        for (int j = 0; j < DD / 4; ++j) {
            float4 m = row[j];
            a0 = fmaf(m.x, m.x, a0);
            a1 = fmaf(m.y, m.y, a1);
            a2 = fmaf(m.z, m.z, a2);
            a3 = fmaf(m.w, m.w, a3);
        }
        s_m2[r] = (a0 + a1) + (a2 + a3);
        s_hist[r] = 0u;
    }

    // Token x into registers, pre-scaled by -2 (exact pow2).
    float4 xv2[16];
    const float4* __restrict__ xg =
        (const float4*)(x + (size_t)t * (BH * DD) + h * DD);
#pragma unroll
    for (int j = 0; j < 16; ++j) {
        float4 v = xg[j];
        xv2[j] = make_float4(-2.f * v.x, -2.f * v.y, -2.f * v.z, -2.f * v.w);
    }

    // Chunked argmin: stage 128 rows, scan them, repeat. dist = |m|^2 - 2 x.m
    float best = 3.4e38f;
    int bid = 0;
    for (int c = 0; c < KK / CH; ++c) {
        __syncthreads();                       // protect s_mrow reuse
        const float4* src = mh + c * CH * (DD / 4);
        for (int j = tid; j < CH * (DD / 4); j += 256) s_mrow[j] = src[j];
        __syncthreads();

        const int kbase = c * CH;
        for (int kk = 0; kk < CH; ++kk) {
            const float4* row = &s_mrow[kk * (DD / 4)];  // uniform -> broadcast
            float a0 = s_m2[kbase + kk], a1 = 0.f, a2 = 0.f, a3 = 0.f;
#pragma unroll
            for (int j = 0; j < 16; ++j) {
                float4 m = row[j];
                a0 = fmaf(xv2[j].x, m.x, a0);
                a1 = fmaf(xv2[j].y, m.y, a1);
                a2 = fmaf(xv2[j].z, m.z, a2);
                a3 = fmaf(xv2[j].w, m.w, a3);
            }
            float dist = (a0 + a1) + (a2 + a3);
            if (dist < best) { best = dist; bid = kbase + kk; }  // strict <
        }
    }

    out_ids[(size_t)t * BH + h] = (float)bid;   // [b,n,h] layout

    // LDS histogram, then sparse flush to global
    atomicAdd(&s_hist[bid], 1u);
    __syncthreads();
    for (int r = tid; r < KK; r += 256) {
        unsigned int v = s_hist[r];
        if (v) atomicAdd(&g_hist[h * KK + r], v);
    }
}

// ---------------------------------------------------------------------------
// Kernel 2: per-head exclusive prefix sum of counts -> cursor.
// grid = BH blocks, 512 threads.
// ---------------------------------------------------------------------------
__global__ __launch_bounds__(512) void vq_scan(
    const unsigned int* __restrict__ g_hist,
    unsigned int* __restrict__ cursor)
{
    const int h = blockIdx.x;
    const int tid = threadIdx.x;
    __shared__ unsigned int s[KK];

    unsigned int own = g_hist[h * KK + tid];
    s[tid] = own;
    __syncthreads();
    for (int off = 1; off < KK; off <<= 1) {
        unsigned int v = 0;
        if (tid >= off) v = s[tid - off];
        __syncthreads();
        s[tid] += v;
        __syncthreads();
    }
    cursor[h * KK + tid] = s[tid] - own;   // exclusive
}

// ---------------------------------------------------------------------------
// Kernel 3: scatter token indices into buckets. One cursor atomic per token.
// grid = (NT/256, BH), block = 256.
// ---------------------------------------------------------------------------
__global__ __launch_bounds__(256) void vq_scatter(
    const float* __restrict__ out_ids,
    unsigned int* __restrict__ cursor,
    unsigned int* __restrict__ tokbuf)   // [BH*NT]
{
    const int h = blockIdx.y;
    const int t = blockIdx.x * 256 + threadIdx.x;
    int id = (int)out_ids[(size_t)t * BH + h];
    unsigned int slot = atomicAdd(&cursor[h * KK + id], 1u);
    tokbuf[(size_t)h * NT + slot] = (unsigned int)t;
}

// ---------------------------------------------------------------------------
// Kernel 4: one BLOCK (4 waves) per (h,k) bucket. Token dim split across
// waves, 4-deep ILP per wave (16 independent chains total) -> kills the
// straggler-bucket serial-latency tail. lane = dim. Zero atomics, fused EMA.
// grid = BH*KK blocks of 256.
// ---------------------------------------------------------------------------
__global__ __launch_bounds__(256) void vq_gather(
    const float* __restrict__ x,
    const float* __restrict__ means,
    const unsigned int* __restrict__ g_hist,
    const unsigned int* __restrict__ cursor,   // now offset+count
    const unsigned int* __restrict__ tokbuf,
    float* __restrict__ out_means)
{
    const int w    = blockIdx.x;            // bucket id (h*KK+k)
    const int wid  = threadIdx.x >> 6;      // wave 0..3
    const int lane = threadIdx.x & 63;
    const int h    = w >> 9;

    const unsigned int cnt = g_hist[w];
    const unsigned int off = cursor[w] - cnt;
    const unsigned int* tb = tokbuf + (size_t)h * NT + off;
    const float* xb = x + h * DD + lane;

    float a0 = 0.f, a1 = 0.f, a2 = 0.f, a3 = 0.f;
    unsigned int i = wid;
    for (; i + 12 < cnt; i += 16) {          // 4 independent loads in flight
        unsigned int t0 = tb[i], t1 = tb[i + 4], t2 = tb[i + 8], t3 = tb[i + 12];
        a0 += xb[(size_t)t0 * (BH * DD)];
        a1 += xb[(size_t)t1 * (BH * DD)];
        a2 += xb[(size_t)t2 * (BH * DD)];
        a3 += xb[(size_t)t3 * (BH * DD)];
    }
    for (; i < cnt; i += 4)
        a0 += xb[(size_t)tb[i] * (BH * DD)];

    __shared__ float sp[4][DD];
    sp[wid][lane] = (a0 + a1) + (a2 + a3);
    __syncthreads();
    if (wid == 0) {
        float s = (sp[0][lane] + sp[1][lane]) + (sp[2][lane] + sp[3][lane]);
        float nm = s / (1e-6f + (float)cnt);
        float m  = means[(size_t)w * DD + lane];
        out_means[(size_t)w * DD + lane] = 0.001f * nm + 0.999f * m;
    }
}

extern "C" void kernel_launch(void* const* d_in, const int* in_sizes, int n_in,
                              void* d_out, int out_size, void* d_ws, size_t ws_size,
                              hipStream_t stream) {
    const float* x     = (const float*)d_in[0];   // [4,4096,512] f32
    const float* means = (const float*)d_in[1];   // [8,512,64]  f32

    float* out       = (float*)d_out;
    float* out_ids   = out;            // first 131072 floats
    float* out_means = out + IDS_N;    // next 262144 floats

    unsigned int* g_hist = (unsigned int*)d_ws;          // 4096
    unsigned int* cursor = g_hist + BH * KK;             // 4096
    unsigned int* tokbuf = cursor + BH * KK;             // 131072

    // zero hist (cursor is fully written by vq_scan; keep 32 KB memset cheap)
    hipMemsetAsync(g_hist, 0, BH * KK * sizeof(unsigned int), stream);

    dim3 grid(NT / 256, BH);
    vq_assign <<<grid, dim3(256), 0, stream>>>(x, means, out_ids, g_hist);
    vq_scan   <<<BH, dim3(512), 0, stream>>>(g_hist, cursor);
    vq_scatter<<<grid, dim3(256), 0, stream>>>(out_ids, cursor, tokbuf);
    vq_gather <<<BH * KK, dim3(256), 0, stream>>>(
        x, means, g_hist, cursor, tokbuf, out_means);
}